// Round 1
// baseline (378.758 us; speedup 1.0000x reference)
//
#include <hip/hip_runtime.h>
#include <cstdint>
#include <cstddef>

#define D_MODEL 1024
#define NHEAD 16
#define HDIM 64
#define BATCH 2
#define SEQ 2048
#define MROWS (BATCH*SEQ)   // 4096

typedef _Float16 f16;
typedef _Float16 f16x8 __attribute__((ext_vector_type(8)));
typedef float f32x4 __attribute__((ext_vector_type(4)));

// async global->LDS, 16B per lane; LDS dest = wave-uniform base + lane*16
__device__ __forceinline__ void gload_lds16(const void* gsrc, void* ldst) {
  __builtin_amdgcn_global_load_lds(
      (__attribute__((address_space(1))) void*)gsrc,
      (__attribute__((address_space(3))) void*)ldst,
      16, 0, 0);
}

// ---------------- cast fp32 -> f16 (contiguous) ----------------
__global__ __launch_bounds__(256) void cast_f16_kernel(
    const float* __restrict__ in, f16* __restrict__ out, int n) {
  int i = (blockIdx.x * 256 + threadIdx.x) * 8;
  if (i >= n) return;
  const float4* p = (const float4*)(in + i);
  float4 a = p[0], b = p[1];
  f16x8 o = { (f16)a.x,(f16)a.y,(f16)a.z,(f16)a.w,
              (f16)b.x,(f16)b.y,(f16)b.z,(f16)b.w };
  *(f16x8*)(out + i) = o;
}

// ---------------- cast+transpose W[K,N] -> Wt[N,K] f16 ----------------
__global__ __launch_bounds__(256) void transpose_cast_kernel(
    const float* __restrict__ W, f16* __restrict__ Wt) {
  __shared__ float tile[32][33];
  int n0 = blockIdx.x * 32, k0 = blockIdx.y * 32;
  int tx = threadIdx.x, ty = threadIdx.y;  // block (32,8)
  #pragma unroll
  for (int j = 0; j < 32; j += 8)
    tile[ty + j][tx] = W[(size_t)(k0 + ty + j) * D_MODEL + n0 + tx];
  __syncthreads();
  #pragma unroll
  for (int j = 0; j < 32; j += 8)
    Wt[(size_t)(n0 + ty + j) * D_MODEL + k0 + tx] = (f16)tile[tx][ty + j];
}

// ---------------- GEMM: C[M,N] = A[M,K] @ Bt[N,K]^T + bias ----------------
// M=4096, N=1024, K=1024 fixed. 128x128 tile, BK=32, 4 waves, 4x4 16x16x32 MFMA.
// MODE 0: fp32 out row-major [M,N]
// MODE 1: f16 out head-major [B,H,S,64]   (for Q, K)
// MODE 2: f16 out head-major transposed [B,H,64,S]  (for V)
template<int MODE>
__global__ __launch_bounds__(256) void gemm_bt(
    const f16* __restrict__ A, const f16* __restrict__ Bt,
    const float* __restrict__ bias, void* __restrict__ out) {
  constexpr int K = 1024;
  __shared__ __align__(16) f16 As[128 * 32];
  __shared__ __align__(16) f16 Bs[128 * 32];
  const int tid = threadIdx.x;
  const int wave = tid >> 6, lane = tid & 63;
  const int bm = blockIdx.y * 128, bn = blockIdx.x * 128;
  const int wm = (wave >> 1) * 64, wn = (wave & 1) * 64;
  const int lr = lane & 15;   // fragment row/col
  const int lq = lane >> 4;   // quad

  f32x4 zero = {0.f, 0.f, 0.f, 0.f};
  f32x4 acc[4][4];
  #pragma unroll
  for (int i = 0; i < 4; i++)
    #pragma unroll
    for (int j = 0; j < 4; j++) acc[i][j] = zero;

  const int u0 = wave * 128 + lane;  // chunk (wave*2), lane's 16B unit
  const int u1 = u0 + 64;            // chunk (wave*2+1)

  for (int k0 = 0; k0 < K; k0 += 32) {
    __syncthreads();
    {
      const f16* Ab = A  + (size_t)bm * K + k0;
      const f16* Bb = Bt + (size_t)bn * K + k0;
      gload_lds16(Ab + (u0 >> 2) * K + (u0 & 3) * 8, As + (wave * 2 + 0) * 512);
      gload_lds16(Ab + (u1 >> 2) * K + (u1 & 3) * 8, As + (wave * 2 + 1) * 512);
      gload_lds16(Bb + (u0 >> 2) * K + (u0 & 3) * 8, Bs + (wave * 2 + 0) * 512);
      gload_lds16(Bb + (u1 >> 2) * K + (u1 & 3) * 8, Bs + (wave * 2 + 1) * 512);
    }
    __syncthreads();
    f16x8 af[4], bf[4];
    #pragma unroll
    for (int i = 0; i < 4; i++)
      af[i] = *(const f16x8*)(As + (wm + i * 16 + lr) * 32 + lq * 8);
    #pragma unroll
    for (int j = 0; j < 4; j++)
      bf[j] = *(const f16x8*)(Bs + (wn + j * 16 + lr) * 32 + lq * 8);
    #pragma unroll
    for (int i = 0; i < 4; i++)
      #pragma unroll
      for (int j = 0; j < 4; j++)
        acc[i][j] = __builtin_amdgcn_mfma_f32_16x16x32_f16(af[i], bf[j], acc[i][j], 0, 0, 0);
  }

  #pragma unroll
  for (int j = 0; j < 4; j++) {
    const int col = bn + wn + j * 16 + lr;
    const float bj = bias[col];
    #pragma unroll
    for (int i = 0; i < 4; i++) {
      #pragma unroll
      for (int r = 0; r < 4; r++) {
        const int row = bm + wm + i * 16 + lq * 4 + r;
        const float v = acc[i][j][r] + bj;
        if (MODE == 0) {
          ((float*)out)[(size_t)row * D_MODEL + col] = v;
        } else {
          const int b = row >> 11, s = row & 2047;
          const int h = col >> 6, d = col & 63;
          if (MODE == 1)
            ((f16*)out)[(((size_t)b * NHEAD + h) * SEQ + s) * HDIM + d] = (f16)v;
          else
            ((f16*)out)[(((size_t)b * NHEAD + h) * HDIM + d) * SEQ + s] = (f16)v;
        }
      }
    }
  }
}

// ---------------- flash attention ----------------
// Qh,Kh: [B,H,S,64] f16; Vt: [B,H,64,S] f16; out: [B,S,1024] f16
// grid (S/64, H, B), 256 threads = 4 waves, wave handles 16 Q rows.
__global__ __launch_bounds__(256) void flash_kernel(
    const f16* __restrict__ Qh, const f16* __restrict__ Kh,
    const f16* __restrict__ Vt, f16* __restrict__ Oout) {
  __shared__ __align__(16) f16 Ks[64 * 64];
  __shared__ __align__(16) f16 Vs[64 * 64];   // [dim][key]
  __shared__ __align__(16) f16 Ps[4 * 16 * 64];
  const int tid = threadIdx.x, wave = tid >> 6, lane = tid & 63;
  const int lr = lane & 15, lq = lane >> 4;
  const int h = blockIdx.y, b = blockIdx.z;
  const size_t headQK = ((size_t)b * NHEAD + h) * SEQ * HDIM;
  const f16* Qb = Qh + headQK;
  const f16* Kb = Kh + headQK;
  const f16* Vb = Vt + ((size_t)b * NHEAD + h) * HDIM * SEQ;
  const int q0 = blockIdx.x * 64 + wave * 16;
  const float scale = 0.125f;  // 1/sqrt(64)

  f16x8 aq[2];
  #pragma unroll
  for (int t = 0; t < 2; t++)
    aq[t] = *(const f16x8*)(Qb + (size_t)(q0 + lr) * HDIM + t * 32 + lq * 8);

  f32x4 zero = {0.f, 0.f, 0.f, 0.f};
  f32x4 oacc[4];
  #pragma unroll
  for (int j = 0; j < 4; j++) oacc[j] = zero;
  float mrow[4], lrow[4];
  #pragma unroll
  for (int r = 0; r < 4; r++) { mrow[r] = -1e30f; lrow[r] = 0.f; }

  const int u0 = wave * 128 + lane, u1 = u0 + 64;

  for (int kt = 0; kt < SEQ; kt += 64) {
    __syncthreads();
    {
      // K tile: rows kt..kt+64 of [S,64] -> contiguous 8KB
      gload_lds16(Kb + (size_t)kt * HDIM + u0 * 8, Ks + (wave * 2 + 0) * 512);
      gload_lds16(Kb + (size_t)kt * HDIM + u1 * 8, Ks + (wave * 2 + 1) * 512);
      // V tile: [dim][key] rows of 128B from Vt[dim][kt..kt+64]
      gload_lds16(Vb + (size_t)(u0 >> 3) * SEQ + kt + (u0 & 7) * 8, Vs + (wave * 2 + 0) * 512);
      gload_lds16(Vb + (size_t)(u1 >> 3) * SEQ + kt + (u1 & 7) * 8, Vs + (wave * 2 + 1) * 512);
    }
    __syncthreads();

    // S = Q @ K^T  (16 rows x 64 keys per wave)
    f32x4 sc[4];
    #pragma unroll
    for (int j = 0; j < 4; j++) {
      sc[j] = zero;
      #pragma unroll
      for (int t = 0; t < 2; t++) {
        f16x8 bk = *(const f16x8*)(Ks + (j * 16 + lr) * 64 + t * 32 + lq * 8);
        sc[j] = __builtin_amdgcn_mfma_f32_16x16x32_f16(aq[t], bk, sc[j], 0, 0, 0);
      }
    }

    // online softmax (row = lq*4 + r, cols spread over 16 lanes x 4 j)
    float alpha[4], pval[4][4];
    #pragma unroll
    for (int r = 0; r < 4; r++) {
      float m0 = fmaxf(fmaxf(sc[0][r], sc[1][r]), fmaxf(sc[2][r], sc[3][r]));
      #pragma unroll
      for (int d = 1; d < 16; d <<= 1)
        m0 = fmaxf(m0, __shfl_xor(m0, d, 64));
      const float mnew = fmaxf(mrow[r], m0 * scale);
      alpha[r] = __expf(mrow[r] - mnew);
      mrow[r] = mnew;
      float s0 = 0.f;
      #pragma unroll
      for (int j = 0; j < 4; j++) {
        float p = __expf(sc[j][r] * scale - mnew);
        pval[j][r] = p;
        s0 += p;
      }
      #pragma unroll
      for (int d = 1; d < 16; d <<= 1)
        s0 += __shfl_xor(s0, d, 64);
      lrow[r] = lrow[r] * alpha[r] + s0;
    }

    // P -> LDS (C-layout -> A-layout round trip), rescale O
    f16* Pw = Ps + wave * 1024;
    #pragma unroll
    for (int j = 0; j < 4; j++)
      #pragma unroll
      for (int r = 0; r < 4; r++)
        Pw[(lq * 4 + r) * 64 + j * 16 + lr] = (f16)pval[j][r];
    #pragma unroll
    for (int j = 0; j < 4; j++)
      #pragma unroll
      for (int r = 0; r < 4; r++)
        oacc[j][r] *= alpha[r];
    __builtin_amdgcn_s_waitcnt(0);  // ensure wave-local P writes land before reads

    // O += P @ V
    #pragma unroll
    for (int t = 0; t < 2; t++) {
      f16x8 ap = *(const f16x8*)(Pw + lr * 64 + t * 32 + lq * 8);
      #pragma unroll
      for (int j = 0; j < 4; j++) {
        f16x8 bv = *(const f16x8*)(Vs + (j * 16 + lr) * 64 + t * 32 + lq * 8);
        oacc[j] = __builtin_amdgcn_mfma_f32_16x16x32_f16(ap, bv, oacc[j], 0, 0, 0);
      }
    }
  }

  // epilogue: write [B,S,H*64] f16
  #pragma unroll
  for (int j = 0; j < 4; j++) {
    #pragma unroll
    for (int r = 0; r < 4; r++) {
      const int row = q0 + lq * 4 + r;
      const int col = h * HDIM + j * 16 + lr;
      Oout[((size_t)b * SEQ + row) * D_MODEL + col] = (f16)(oacc[j][r] / lrow[r]);
    }
  }
}

extern "C" void kernel_launch(void* const* d_in, const int* in_sizes, int n_in,
                              void* d_out, int out_size, void* d_ws, size_t ws_size,
                              hipStream_t stream) {
  const float* q  = (const float*)d_in[0];
  const float* k  = (const float*)d_in[1];
  const float* v  = (const float*)d_in[2];
  const float* Wq = (const float*)d_in[3];
  const float* bq = (const float*)d_in[4];
  const float* Wk = (const float*)d_in[5];
  const float* bk = (const float*)d_in[6];
  const float* Wv = (const float*)d_in[7];
  const float* bv = (const float*)d_in[8];
  const float* Wo = (const float*)d_in[9];
  const float* bo = (const float*)d_in[10];
  float* out = (float*)d_out;

  char* ws = (char*)d_ws;
  f16* Wt_q = (f16*)(ws + ((size_t)0  << 20));  // 2MB each
  f16* Wt_k = (f16*)(ws + ((size_t)2  << 20));
  f16* Wt_v = (f16*)(ws + ((size_t)4  << 20));
  f16* Wt_o = (f16*)(ws + ((size_t)6  << 20));
  f16* Xf   = (f16*)(ws + ((size_t)8  << 20));  // 8MB, reused for q,k,v casts
  f16* Qh_  = (f16*)(ws + ((size_t)16 << 20));  // 8MB
  f16* Kh_  = (f16*)(ws + ((size_t)24 << 20));  // 8MB
  f16* Vt_  = (f16*)(ws + ((size_t)32 << 20));  // 8MB
  f16* AO   = (f16*)(ws + ((size_t)40 << 20));  // 8MB

  dim3 tb(32, 8), tg(32, 32);
  transpose_cast_kernel<<<tg, tb, 0, stream>>>(Wq, Wt_q);
  transpose_cast_kernel<<<tg, tb, 0, stream>>>(Wk, Wt_k);
  transpose_cast_kernel<<<tg, tb, 0, stream>>>(Wv, Wt_v);
  transpose_cast_kernel<<<tg, tb, 0, stream>>>(Wo, Wt_o);

  const int n = MROWS * D_MODEL;  // 4194304
  dim3 cg(n / 8 / 256);
  dim3 gg(D_MODEL / 128, MROWS / 128);  // (8, 32)

  cast_f16_kernel<<<cg, 256, 0, stream>>>(q, Xf, n);
  gemm_bt<1><<<gg, 256, 0, stream>>>(Xf, Wt_q, bq, Qh_);
  cast_f16_kernel<<<cg, 256, 0, stream>>>(k, Xf, n);
  gemm_bt<1><<<gg, 256, 0, stream>>>(Xf, Wt_k, bk, Kh_);
  cast_f16_kernel<<<cg, 256, 0, stream>>>(v, Xf, n);
  gemm_bt<2><<<gg, 256, 0, stream>>>(Xf, Wt_v, bv, Vt_);

  dim3 fg(SEQ / 64, NHEAD, BATCH);  // (32,16,2)
  flash_kernel<<<fg, 256, 0, stream>>>(Qh_, Kh_, Vt_, AO);

  gemm_bt<0><<<gg, 256, 0, stream>>>(AO, Wt_o, bo, out);
}

// Round 2
// 291.518 us; speedup vs baseline: 1.2993x; 1.2993x over previous
//
#include <hip/hip_runtime.h>
#include <cstdint>
#include <cstddef>

#define D_MODEL 1024
#define NHEAD 16
#define HDIM 64
#define BATCH 2
#define SEQ 2048
#define MROWS (BATCH*SEQ)   // 4096

typedef _Float16 f16;
typedef _Float16 f16x8 __attribute__((ext_vector_type(8)));
typedef float f32x4 __attribute__((ext_vector_type(4)));

// async global->LDS, 16B per lane; LDS dest = wave-uniform base + lane*16
__device__ __forceinline__ void gload_lds16(const void* gsrc, void* ldst) {
  __builtin_amdgcn_global_load_lds(
      (__attribute__((address_space(1))) void*)gsrc,
      (__attribute__((address_space(3))) void*)ldst,
      16, 0, 0);
}

// 16-lane (DPP row) butterfly reductions, result broadcast to all 16 lanes.
// VALU pipe (v_mov_dpp + op), much lower latency than ds_bpermute shuffles.
__device__ __forceinline__ float dpp_max16(float x) {
  float y;
  y = __int_as_float(__builtin_amdgcn_update_dpp(0, __float_as_int(x), 0x128, 0xF, 0xF, true)); // row_ror:8
  x = fmaxf(x, y);
  y = __int_as_float(__builtin_amdgcn_update_dpp(0, __float_as_int(x), 0x124, 0xF, 0xF, true)); // row_ror:4
  x = fmaxf(x, y);
  y = __int_as_float(__builtin_amdgcn_update_dpp(0, __float_as_int(x), 0x04E, 0xF, 0xF, true)); // quad_perm xor2
  x = fmaxf(x, y);
  y = __int_as_float(__builtin_amdgcn_update_dpp(0, __float_as_int(x), 0x0B1, 0xF, 0xF, true)); // quad_perm xor1
  x = fmaxf(x, y);
  return x;
}
__device__ __forceinline__ float dpp_sum16(float x) {
  float y;
  y = __int_as_float(__builtin_amdgcn_update_dpp(0, __float_as_int(x), 0x128, 0xF, 0xF, true));
  x += y;
  y = __int_as_float(__builtin_amdgcn_update_dpp(0, __float_as_int(x), 0x124, 0xF, 0xF, true));
  x += y;
  y = __int_as_float(__builtin_amdgcn_update_dpp(0, __float_as_int(x), 0x04E, 0xF, 0xF, true));
  x += y;
  y = __int_as_float(__builtin_amdgcn_update_dpp(0, __float_as_int(x), 0x0B1, 0xF, 0xF, true));
  x += y;
  return x;
}

// ---------------- cast fp32 -> f16, two tensors selected by blockIdx.y ------
__global__ __launch_bounds__(256) void cast2_kernel(
    const float* __restrict__ in0, const float* __restrict__ in1,
    f16* __restrict__ out0, f16* __restrict__ out1) {
  const float* in = blockIdx.y ? in1 : in0;
  f16* out = blockIdx.y ? out1 : out0;
  int i = (blockIdx.x * 256 + threadIdx.x) * 8;
  const float4* p = (const float4*)(in + i);
  float4 a = p[0], b = p[1];
  f16x8 o = { (f16)a.x,(f16)a.y,(f16)a.z,(f16)a.w,
              (f16)b.x,(f16)b.y,(f16)b.z,(f16)b.w };
  *(f16x8*)(out + i) = o;
}

// ---------------- cast+transpose W[K,N] -> Wt[N,K] f16, 4 mats by z --------
__global__ __launch_bounds__(256) void transpose4_kernel(
    const float* __restrict__ W0, const float* __restrict__ W1,
    const float* __restrict__ W2, const float* __restrict__ W3,
    f16* __restrict__ T0, f16* __restrict__ T1,
    f16* __restrict__ T2, f16* __restrict__ T3) {
  const int z = blockIdx.z;
  const float* W = (z == 0) ? W0 : (z == 1) ? W1 : (z == 2) ? W2 : W3;
  f16* Wt = (z == 0) ? T0 : (z == 1) ? T1 : (z == 2) ? T2 : T3;
  __shared__ float tile[32][33];
  int n0 = blockIdx.x * 32, k0 = blockIdx.y * 32;
  int tx = threadIdx.x, ty = threadIdx.y;  // block (32,8)
  #pragma unroll
  for (int j = 0; j < 32; j += 8)
    tile[ty + j][tx] = W[(size_t)(k0 + ty + j) * D_MODEL + n0 + tx];
  __syncthreads();
  #pragma unroll
  for (int j = 0; j < 32; j += 8)
    Wt[(size_t)(n0 + ty + j) * D_MODEL + k0 + tx] = (f16)tile[tx][ty + j];
}

// ---------------- 8-wave GEMM core: 128x128 tile, BK=32 --------------------
// A[M,K] @ Bt[N,K]^T, K=1024. Block 512 thr = 8 waves, wave does 32x64 (2x4 accs).
__device__ __forceinline__ void gemm_core(
    const f16* __restrict__ A, const f16* __restrict__ Bt,
    f16* As, f16* Bs, f32x4 acc[2][4],
    int bm, int bn, int wave, int lane) {
  constexpr int K = 1024;
  const int lr = lane & 15, lq = lane >> 4;
  const int wm = (wave >> 1) * 32, wn = (wave & 1) * 64;
  const int urow = (wave * 64 + lane) >> 2;   // 0..127
  const int ukc  = (lane & 3) * 8;            // f16 k-offset within BK
  #pragma unroll
  for (int i = 0; i < 2; i++)
    #pragma unroll
    for (int j = 0; j < 4; j++) acc[i][j] = (f32x4){0.f, 0.f, 0.f, 0.f};
  for (int k0 = 0; k0 < K; k0 += 32) {
    __syncthreads();
    gload_lds16(A  + (size_t)(bm + urow) * K + k0 + ukc, As + wave * 512);
    gload_lds16(Bt + (size_t)(bn + urow) * K + k0 + ukc, Bs + wave * 512);
    __syncthreads();
    f16x8 af[2], bf[4];
    #pragma unroll
    for (int i = 0; i < 2; i++)
      af[i] = *(const f16x8*)(As + (wm + i * 16 + lr) * 32 + lq * 8);
    #pragma unroll
    for (int j = 0; j < 4; j++)
      bf[j] = *(const f16x8*)(Bs + (wn + j * 16 + lr) * 32 + lq * 8);
    #pragma unroll
    for (int i = 0; i < 2; i++)
      #pragma unroll
      for (int j = 0; j < 4; j++)
        acc[i][j] = __builtin_amdgcn_mfma_f32_16x16x32_f16(af[i], bf[j], acc[i][j], 0, 0, 0);
  }
}

// Q and K projections fused via blockIdx.z; epilogue: f16 head-major [B,H,S,64]
__global__ __launch_bounds__(512) void gemm_qk2(
    const f16* __restrict__ Xq, const f16* __restrict__ Xk,
    const f16* __restrict__ Wtq, const f16* __restrict__ Wtk,
    const float* __restrict__ bq, const float* __restrict__ bk,
    f16* __restrict__ Qh, f16* __restrict__ Kh) {
  __shared__ __align__(16) f16 As[128 * 32];
  __shared__ __align__(16) f16 Bs[128 * 32];
  const int z = blockIdx.z;
  const f16* A  = z ? Xk : Xq;
  const f16* Bt = z ? Wtk : Wtq;
  const float* bias = z ? bk : bq;
  f16* out = z ? Kh : Qh;
  const int tid = threadIdx.x, wave = tid >> 6, lane = tid & 63;
  const int lr = lane & 15, lq = lane >> 4;
  const int bm = blockIdx.y * 128, bn = blockIdx.x * 128;
  const int wm = (wave >> 1) * 32, wn = (wave & 1) * 64;
  f32x4 acc[2][4];
  gemm_core(A, Bt, As, Bs, acc, bm, bn, wave, lane);
  #pragma unroll
  for (int j = 0; j < 4; j++) {
    const int col = bn + wn + j * 16 + lr;
    const float bj = bias[col];
    const int h = col >> 6, d = col & 63;
    #pragma unroll
    for (int i = 0; i < 2; i++) {
      #pragma unroll
      for (int r = 0; r < 4; r++) {
        const int row = bm + wm + i * 16 + lq * 4 + r;
        const int b = row >> 11, s = row & 2047;
        out[(((size_t)b * NHEAD + h) * SEQ + s) * HDIM + d] = (f16)(acc[i][j][r] + bj);
      }
    }
  }
}

// V projection; epilogue: f16 head-major transposed [B,H,64,S]
__global__ __launch_bounds__(512) void gemm_v(
    const f16* __restrict__ Xv, const f16* __restrict__ Wtv,
    const float* __restrict__ bv, f16* __restrict__ Vt) {
  __shared__ __align__(16) f16 As[128 * 32];
  __shared__ __align__(16) f16 Bs[128 * 32];
  const int tid = threadIdx.x, wave = tid >> 6, lane = tid & 63;
  const int lr = lane & 15, lq = lane >> 4;
  const int bm = blockIdx.y * 128, bn = blockIdx.x * 128;
  const int wm = (wave >> 1) * 32, wn = (wave & 1) * 64;
  f32x4 acc[2][4];
  gemm_core(Xv, Wtv, As, Bs, acc, bm, bn, wave, lane);
  #pragma unroll
  for (int j = 0; j < 4; j++) {
    const int col = bn + wn + j * 16 + lr;
    const float bj = bv[col];
    const int h = col >> 6, d = col & 63;
    #pragma unroll
    for (int i = 0; i < 2; i++) {
      #pragma unroll
      for (int r = 0; r < 4; r++) {
        const int row = bm + wm + i * 16 + lq * 4 + r;
        const int b = row >> 11, s = row & 2047;
        Vt[(((size_t)b * NHEAD + h) * HDIM + d) * SEQ + s] = (f16)(acc[i][j][r] + bj);
      }
    }
  }
}

// Output projection; epilogue: fp32 row-major [M, D_MODEL]
__global__ __launch_bounds__(512) void gemm_o(
    const f16* __restrict__ AO, const f16* __restrict__ Wto,
    const float* __restrict__ bo, float* __restrict__ out) {
  __shared__ __align__(16) f16 As[128 * 32];
  __shared__ __align__(16) f16 Bs[128 * 32];
  const int tid = threadIdx.x, wave = tid >> 6, lane = tid & 63;
  const int lr = lane & 15, lq = lane >> 4;
  const int bm = blockIdx.y * 128, bn = blockIdx.x * 128;
  const int wm = (wave >> 1) * 32, wn = (wave & 1) * 64;
  f32x4 acc[2][4];
  gemm_core(AO, Wto, As, Bs, acc, bm, bn, wave, lane);
  #pragma unroll
  for (int j = 0; j < 4; j++) {
    const int col = bn + wn + j * 16 + lr;
    const float bj = bo[col];
    #pragma unroll
    for (int i = 0; i < 2; i++) {
      #pragma unroll
      for (int r = 0; r < 4; r++) {
        const int row = bm + wm + i * 16 + lq * 4 + r;
        out[(size_t)row * D_MODEL + col] = acc[i][j][r] + bj;
      }
    }
  }
}

// ---------------- flash attention ----------------
// Qh,Kh: [B,H,S,64] f16; Vt: [B,H,64,S] f16; out AO: [B,S,1024] f16
// grid (S/64, H, B), 256 thr = 4 waves, wave handles 16 Q rows.
#define PSTRIDE 72   // padded P row stride (f16): breaks bank aliasing, keeps 16B align
__global__ __launch_bounds__(256) void flash_kernel(
    const f16* __restrict__ Qh, const f16* __restrict__ Kh,
    const f16* __restrict__ Vt, f16* __restrict__ Oout) {
  __shared__ __align__(16) f16 Ks[64 * 64];
  __shared__ __align__(16) f16 Vs[64 * 64];          // [dim][key]
  __shared__ __align__(16) f16 Ps[4 * 16 * PSTRIDE]; // per-wave P, padded
  const int tid = threadIdx.x, wave = tid >> 6, lane = tid & 63;
  const int lr = lane & 15, lq = lane >> 4;
  const int h = blockIdx.y, b = blockIdx.z;
  const size_t headQK = ((size_t)b * NHEAD + h) * SEQ * HDIM;
  const f16* Qb = Qh + headQK;
  const f16* Kb = Kh + headQK;
  const f16* Vb = Vt + ((size_t)b * NHEAD + h) * HDIM * SEQ;
  const int q0 = blockIdx.x * 64 + wave * 16;

  // Q fragment, pre-scaled by 1/sqrt(64)=0.125 (exact in f16)
  f16x8 aq[2];
  #pragma unroll
  for (int t = 0; t < 2; t++) {
    f16x8 v = *(const f16x8*)(Qb + (size_t)(q0 + lr) * HDIM + t * 32 + lq * 8);
    #pragma unroll
    for (int e = 0; e < 8; e++) v[e] = v[e] * (f16)0.125f;
    aq[t] = v;
  }

  f32x4 zero = {0.f, 0.f, 0.f, 0.f};
  f32x4 oacc[4];
  #pragma unroll
  for (int j = 0; j < 4; j++) oacc[j] = zero;
  float mrow[4], lsum[4];   // lsum: PER-LANE partial (deferred cross-lane reduce)
  #pragma unroll
  for (int r = 0; r < 4; r++) { mrow[r] = -1e30f; lsum[r] = 0.f; }

  const int u0 = wave * 128 + lane, u1 = u0 + 64;
  f16* Pw = Ps + wave * 16 * PSTRIDE;

  for (int kt = 0; kt < SEQ; kt += 64) {
    __syncthreads();
    {
      gload_lds16(Kb + (size_t)kt * HDIM + u0 * 8, Ks + (wave * 2 + 0) * 512);
      gload_lds16(Kb + (size_t)kt * HDIM + u1 * 8, Ks + (wave * 2 + 1) * 512);
      gload_lds16(Vb + (size_t)(u0 >> 3) * SEQ + kt + (u0 & 7) * 8, Vs + (wave * 2 + 0) * 512);
      gload_lds16(Vb + (size_t)(u1 >> 3) * SEQ + kt + (u1 & 7) * 8, Vs + (wave * 2 + 1) * 512);
    }
    __syncthreads();

    // S = Q @ K^T (already scaled), 16 rows x 64 keys per wave
    f32x4 sc[4];
    #pragma unroll
    for (int j = 0; j < 4; j++) {
      sc[j] = zero;
      #pragma unroll
      for (int t = 0; t < 2; t++) {
        f16x8 bk = *(const f16x8*)(Ks + (j * 16 + lr) * 64 + t * 32 + lq * 8);
        sc[j] = __builtin_amdgcn_mfma_f32_16x16x32_f16(aq[t], bk, sc[j], 0, 0, 0);
      }
    }

    // online softmax: DPP max reduce; sum kept per-lane (linear, reduce at end)
    #pragma unroll
    for (int r = 0; r < 4; r++) {
      float m0 = fmaxf(fmaxf(sc[0][r], sc[1][r]), fmaxf(sc[2][r], sc[3][r]));
      m0 = dpp_max16(m0);
      const float mnew = fmaxf(mrow[r], m0);
      const float alpha = __expf(mrow[r] - mnew);
      mrow[r] = mnew;
      float s = 0.f;
      #pragma unroll
      for (int j = 0; j < 4; j++) {
        float p = __expf(sc[j][r] - mnew);
        Pw[(lq * 4 + r) * PSTRIDE + j * 16 + lr] = (f16)p;
        s += p;
      }
      lsum[r] = lsum[r] * alpha + s;
      #pragma unroll
      for (int j = 0; j < 4; j++) oacc[j][r] *= alpha;
    }
    __builtin_amdgcn_s_waitcnt(0);  // wave-local P writes -> reads

    // O += P @ V
    #pragma unroll
    for (int t = 0; t < 2; t++) {
      f16x8 ap = *(const f16x8*)(Pw + lr * PSTRIDE + t * 32 + lq * 8);
      #pragma unroll
      for (int j = 0; j < 4; j++) {
        f16x8 bv = *(const f16x8*)(Vs + (j * 16 + lr) * 64 + t * 32 + lq * 8);
        oacc[j] = __builtin_amdgcn_mfma_f32_16x16x32_f16(ap, bv, oacc[j], 0, 0, 0);
      }
    }
  }

  // final cross-lane sum reduce + epilogue [B,S,H*64] f16
  float inv[4];
  #pragma unroll
  for (int r = 0; r < 4; r++) inv[r] = 1.0f / dpp_sum16(lsum[r]);
  #pragma unroll
  for (int j = 0; j < 4; j++) {
    #pragma unroll
    for (int r = 0; r < 4; r++) {
      const int row = q0 + lq * 4 + r;
      const int col = h * HDIM + j * 16 + lr;
      Oout[((size_t)b * SEQ + row) * D_MODEL + col] = (f16)(oacc[j][r] * inv[r]);
    }
  }
}

extern "C" void kernel_launch(void* const* d_in, const int* in_sizes, int n_in,
                              void* d_out, int out_size, void* d_ws, size_t ws_size,
                              hipStream_t stream) {
  const float* q  = (const float*)d_in[0];
  const float* k  = (const float*)d_in[1];
  const float* v  = (const float*)d_in[2];
  const float* Wq = (const float*)d_in[3];
  const float* bq = (const float*)d_in[4];
  const float* Wk = (const float*)d_in[5];
  const float* bk = (const float*)d_in[6];
  const float* Wv = (const float*)d_in[7];
  const float* bv = (const float*)d_in[8];
  const float* Wo = (const float*)d_in[9];
  const float* bo = (const float*)d_in[10];
  float* out = (float*)d_out;

  // 48 MB workspace layout (proven size), buffers reused across phases:
  char* ws = (char*)d_ws;
  f16* Wt_q = (f16*)(ws + ((size_t)0  << 20));
  f16* Wt_k = (f16*)(ws + ((size_t)2  << 20));
  f16* Wt_v = (f16*)(ws + ((size_t)4  << 20));
  f16* Wt_o = (f16*)(ws + ((size_t)6  << 20));
  f16* Xq   = (f16*)(ws + ((size_t)8  << 20));  // later reused for Xv
  f16* Xk   = (f16*)(ws + ((size_t)16 << 20));  // later reused for AO
  f16* Qh_  = (f16*)(ws + ((size_t)24 << 20));
  f16* Kh_  = (f16*)(ws + ((size_t)32 << 20));
  f16* Vt_  = (f16*)(ws + ((size_t)40 << 20));
  f16* AO   = Xk;

  dim3 tb(32, 8);
  transpose4_kernel<<<dim3(32, 32, 4), tb, 0, stream>>>(
      Wq, Wk, Wv, Wo, Wt_q, Wt_k, Wt_v, Wt_o);

  cast2_kernel<<<dim3(2048, 2), 256, 0, stream>>>(q, k, Xq, Xk);
  gemm_qk2<<<dim3(8, 32, 2), 512, 0, stream>>>(Xq, Xk, Wt_q, Wt_k, bq, bk, Qh_, Kh_);

  cast2_kernel<<<dim3(2048, 1), 256, 0, stream>>>(v, v, Xq, Xq);
  gemm_v<<<dim3(8, 32), 512, 0, stream>>>(Xq, Wt_v, bv, Vt_);

  flash_kernel<<<dim3(SEQ / 64, NHEAD, BATCH), 256, 0, stream>>>(Qh_, Kh_, Vt_, AO);

  gemm_o<<<dim3(8, 32), 512, 0, stream>>>(AO, Wt_o, bo, out);
}